// Round 9
// baseline (305.568 us; speedup 1.0000x reference)
//
#include <hip/hip_runtime.h>

// y[m,o] = sum_k x[m,k] * (W[o,k] + dW[o,k]) + bias[o],  W int4-dequant.
// M=8192, N=4096(OUT), K=4096(IN).
//
// Round 9: occupancy schedule. 128x256 tile, BK=32, 3 LDS bufs x 24KB = 72KB
// -> 2 blocks/CU (16 waves, 4/SIMD): one block's MFMA hides the other's
// barrier/vmcnt stalls. 8 waves = 2M x 4N of 64x64; acc = 64 VGPR;
// __launch_bounds__(512,4) caps at 128 VGPR for 4 waves/SIMD.
// Per iter t: RD(buf t%3); STAGE(t+2 -> buf (t+2)%3); WAITV(3); LGKM(0);
// BAR; MFMA. lgkmcnt(0) before BAR => no ds_read in flight across barriers,
// so STAGE (pre-bar, targets buf read at t-1, reads done pre-BAR(t-1)) is
// race-free. WAITV(3) keeps newest tile's 3 loads in flight; stage->wait
// gap ~ 1 tile wall >> HBM latency.
// Pack kernels / fragment format unchanged from r7 (validated, conflict-free).

#define M_DIM 8192
#define N_DIM 4096
#define K_DIM 4096
#define NUMEL (N_DIM * K_DIM)

typedef _Float16 half_t;
typedef __attribute__((ext_vector_type(4))) _Float16 half4v;
typedef __attribute__((ext_vector_type(8))) _Float16 half8v;
typedef __attribute__((ext_vector_type(4))) float float4v;
typedef __attribute__((ext_vector_type(4))) int int4v;

#define KTILES 64                // 64-K packed tiles per 128-row panel
#define LDT 72                   // fused-fallback padded row stride

static __device__ __forceinline__ void gload16(const void* g, void* l) {
    __builtin_amdgcn_global_load_lds(
        (const __attribute__((address_space(1))) void*)g,
        (__attribute__((address_space(3))) void*)l, 16, 0, 0);
}

// ---------- Phase 1a: dequant+delta -> fp16, fragment-packed (r7) ----------
__global__ __launch_bounds__(256) void k_pack_w(
    const int* __restrict__ qp, const float* __restrict__ sc,
    const float* __restrict__ zr, const float* __restrict__ dwt,
    unsigned char* __restrict__ Wp)
{
    const size_t o = ((size_t)blockIdx.x * 256 + threadIdx.x) << 4;
    const int chunk16 = (int)(o >> 14);          // panel*64 + kt
    const int c  = (int)(o >> 10) & 15;          // rt*2 + ks
    const int ln = (int)(o >> 4) & 63;
    const int n = (chunk16 >> 6) * 128 + (c >> 1) * 16 + (ln & 15);
    const int k = (chunk16 & 63) * 64 + (c & 1) * 32 + (ln >> 4) * 8;
    const long flat = (long)n * K_DIM + k;
    const int g = n * 32 + (k >> 7);
    const float s = sc[g];
    const float zs = zr[g] * s;
    int4v q4 = *(const int4v*)(qp + (flat >> 1));
    float4v d0 = *(const float4v*)(dwt + flat);
    float4v d1 = *(const float4v*)(dwt + flat + 4);
    float d[8] = {d0[0], d0[1], d0[2], d0[3], d1[0], d1[1], d1[2], d1[3]};
    half8v vh;
#pragma unroll
    for (int j = 0; j < 4; ++j) {
        vh[2*j]   = (half_t)fmaf((float)(q4[j] & 15),        s, d[2*j]   - zs);
        vh[2*j+1] = (half_t)fmaf((float)((q4[j] >> 4) & 15), s, d[2*j+1] - zs);
    }
    *(half8v*)(Wp + o) = vh;
}

// ---------- Phase 1b: x fp32 -> fp16, fragment-packed (r7) ----------
__global__ __launch_bounds__(256) void k_pack_x(
    const float* __restrict__ X, unsigned char* __restrict__ Xp)
{
    const size_t o = ((size_t)blockIdx.x * 256 + threadIdx.x) << 4;
    const int chunk16 = (int)(o >> 14);
    const int c  = (int)(o >> 10) & 15;
    const int ln = (int)(o >> 4) & 63;
    const int m = (chunk16 >> 6) * 128 + (c >> 1) * 16 + (ln & 15);
    const int k = (chunk16 & 63) * 64 + (c & 1) * 32 + (ln >> 4) * 8;
    const float* src = X + (size_t)m * K_DIM + k;
    float4v x0 = *(const float4v*)(src);
    float4v x1 = *(const float4v*)(src + 4);
    half8v vh;
    vh[0] = (half_t)x0[0]; vh[1] = (half_t)x0[1];
    vh[2] = (half_t)x0[2]; vh[3] = (half_t)x0[3];
    vh[4] = (half_t)x1[0]; vh[5] = (half_t)x1[1];
    vh[6] = (half_t)x1[2]; vh[7] = (half_t)x1[3];
    *(half8v*)(Xp + o) = vh;
}

// ---------- occupancy GEMM: 128x256, BK=32, 3 bufs, 2 blocks/CU ----------
#define BARX() do { __builtin_amdgcn_sched_barrier(0); \
                    __builtin_amdgcn_s_barrier(); \
                    __builtin_amdgcn_sched_barrier(0); } while(0)
#define WAITV(N) do { asm volatile("s_waitcnt vmcnt(" #N ")" ::: "memory"); \
                      __builtin_amdgcn_sched_barrier(0); } while(0)
#define LGKM0() do { asm volatile("s_waitcnt lgkmcnt(0)" ::: "memory"); \
                     __builtin_amdgcn_sched_barrier(0); } while(0)

#define STAGE(BUF, T) do { \
    const size_t ko_ = ((size_t)((T) >> 1) << 14) + (size_t)(((T) & 1) << 10); \
    gload16(aB + ko_,  &lds[BUF][sdst]); \
    gload16(bB0 + ko_, &lds[BUF][sdst + 8192]); \
    gload16(bB1 + ko_, &lds[BUF][sdst + 16384]); \
} while(0)

#define RD_AB(BUF) do { \
_Pragma("unroll") for (int i_ = 0; i_ < 4; ++i_) \
        ah[i_] = *(const half8v*)(&lds[BUF][aoff + (i_ << 10)]); \
_Pragma("unroll") for (int j_ = 0; j_ < 4; ++j_) \
        bh[j_] = *(const half8v*)(&lds[BUF][boff + (j_ << 10)]); \
} while(0)

#define MFMA16() do { \
    __builtin_amdgcn_s_setprio(1); \
_Pragma("unroll") for (int i_ = 0; i_ < 4; ++i_) \
_Pragma("unroll") for (int j_ = 0; j_ < 4; ++j_) \
        acc[i_][j_] = __builtin_amdgcn_mfma_f32_16x16x32_f16( \
            ah[i_], bh[j_], acc[i_][j_], 0, 0, 0); \
    __builtin_amdgcn_s_setprio(0); \
} while(0)

// steady-state step: read RB, stage T+2 into SB, wait, barrier, compute
#define STEP(RB, SB, T) do { \
    RD_AB(RB); \
    STAGE(SB, (T) + 2); \
    WAITV(3); \
    LGKM0(); \
    BARX(); \
    MFMA16(); \
} while(0)

__global__ __launch_bounds__(512, 4) void k_gemm_occ(
    const unsigned char* __restrict__ Apk, const unsigned char* __restrict__ Bpk,
    const float* __restrict__ bias, float* __restrict__ Y)
{
    __shared__ __align__(16) unsigned char lds[3][24576];  // [buf][A 8K|B0 8K|B1 8K]

    const int tid  = threadIdx.x;
    const int lane = tid & 63;
    const int wave = tid >> 6;
    const int wm2 = wave >> 2;             // 0..1: M 64-half
    const int wn2 = wave & 3;              // 0..3: N 64-quarter
    const int lane16 = lane << 4;
    const int aoff = (wm2 << 12) + lane16;
    const int boff = 8192 + ((wn2 >> 1) << 13) + ((wn2 & 1) << 12) + lane16;
    const int sdst = tid << 4;

    // XCD swizzle: 1024 blocks, 8 XCDs, 128 chunks each (bijective)
    const int wg = blockIdx.x;
    const int swg = (wg & 7) * 128 + (wg >> 3);
    const int bn = swg & 15;               // N_DIM/256 = 16
    const int bm = swg >> 4;               // M_DIM/128 = 64

    // per-thread global stage sources (chunk = tid>>6, lane slot = tid&63)
    const size_t thoff = ((size_t)(tid >> 6) << 11) + (size_t)((tid & 63) << 4);
    const unsigned char* aB  = Apk + ((size_t)bm << 20) + thoff;
    const unsigned char* bB0 = Bpk + ((size_t)(2 * bn) << 20) + thoff;
    const unsigned char* bB1 = Bpk + ((size_t)(2 * bn + 1) << 20) + thoff;

    half8v ah[4], bh[4];
    float4v acc[4][4];
    const float4v zero4 = {0.f, 0.f, 0.f, 0.f};
#pragma unroll
    for (int i = 0; i < 4; ++i)
#pragma unroll
        for (int j = 0; j < 4; ++j) acc[i][j] = zero4;

    // ---- prologue: stage tiles 0,1 ----
    STAGE(0, 0);
    STAGE(1, 1);
    WAITV(3);      // tile0 resident (tile1's 3 stay in flight)
    BARX();

    // ---- 42 x 3 steady steps: tiles 0..125, stages 2..127 ----
    for (int it = 0; it < 42; ++it) {
        const int t = it * 3;
        STEP(0, 2, t);
        STEP(1, 0, t + 1);
        STEP(2, 1, t + 2);
    }

    // ---- tail: tile 126 (buf0), tile 127 (buf1) ----
    RD_AB(0);
    WAITV(0);      // drain tile 127's loads
    LGKM0();
    BARX();
    MFMA16();
    RD_AB(1);
    LGKM0();
    MFMA16();

    // ---- epilogue: 16x16 C/D map col=lane&15, row=(lane>>4)*4+reg ----
    const long m0 = (long)bm * 128 + wm2 * 64;
    const long n0 = (long)bn * 256 + wn2 * 64;
#pragma unroll
    for (int i = 0; i < 4; ++i) {
        const long row = m0 + i * 16 + (lane >> 4) * 4;
#pragma unroll
        for (int j = 0; j < 4; ++j) {
            const long col = n0 + j * 16 + (lane & 15);
            const float b = bias[col];
#pragma unroll
            for (int r = 0; r < 4; ++r)
                Y[(row + r) * N_DIM + col] = acc[i][j][r] + b;
        }
    }
}

// ---------- fallback (no workspace): fused dequant 128x128 GEMM ----------
__global__ __launch_bounds__(256, 2) void k_gemm_fused(
    const float* __restrict__ X, const int* __restrict__ qp,
    const float* __restrict__ sc, const float* __restrict__ zr,
    const float* __restrict__ dwt,
    const float* __restrict__ bias, float* __restrict__ Y)
{
    __shared__ __align__(16) half_t Ah[128 * LDT];
    __shared__ __align__(16) half_t Bh[128 * LDT];

    const int tid  = threadIdx.x;
    const int lane = tid & 63;
    const int wave = tid >> 6;
    const int wm = wave >> 1, wn = wave & 1;
    const int bn = blockIdx.x & 31;
    const int bm = blockIdx.x >> 5;
    const long m0 = (long)bm * 128;
    const long n0 = (long)bn * 128;
    const int fr = lane & 15;
    const int ko = (lane >> 4) * 8;

    const float4v zero4 = {0.f, 0.f, 0.f, 0.f};
    float4v acc[4][4];
#pragma unroll
    for (int i = 0; i < 4; ++i)
#pragma unroll
        for (int j = 0; j < 4; ++j) acc[i][j] = zero4;

    for (int k0 = 0; k0 < K_DIM; k0 += 64) {
        {
            const int ar = tid >> 4;
            const int ac = (tid & 15) * 4;
#pragma unroll
            for (int rr = 0; rr < 8; ++rr) {
                const int row = ar + rr * 16;
                float4v xv = *(const float4v*)(X + (m0 + row) * K_DIM + k0 + ac);
                half4v h;
#pragma unroll
                for (int j = 0; j < 4; ++j) h[j] = (half_t)xv[j];
                *(half4v*)(Ah + row * LDT + ac) = h;
            }
        }
        {
            const int cr = tid >> 3;
            const int cc = (tid & 7) * 8;
#pragma unroll
            for (int rr = 0; rr < 4; ++rr) {
                const int row = cr + rr * 32;
                const long n = n0 + row;
                const int g = (int)(n * 32 + (k0 >> 7));
                const float s = sc[g];
                const float zs = zr[g] * s;
                const long flat = n * K_DIM + k0 + cc;
                int4v q4 = *(const int4v*)(qp + (flat >> 1));
                float4v d0 = *(const float4v*)(dwt + flat);
                float4v d1 = *(const float4v*)(dwt + flat + 4);
                float d[8] = {d0[0], d0[1], d0[2], d0[3], d1[0], d1[1], d1[2], d1[3]};
                half8v vh;
#pragma unroll
                for (int j = 0; j < 4; ++j) {
                    vh[2*j]   = (half_t)fmaf((float)(q4[j] & 15),        s, d[2*j]   - zs);
                    vh[2*j+1] = (half_t)fmaf((float)((q4[j] >> 4) & 15), s, d[2*j+1] - zs);
                }
                *(half8v*)(Bh + row * LDT + cc) = vh;
            }
        }
        __syncthreads();
#pragma unroll
        for (int ks = 0; ks < 2; ++ks) {
            const int kk = ks * 32 + ko;
            half8v a2[4], b2[4];
#pragma unroll
            for (int i = 0; i < 4; ++i) {
                a2[i] = *(const half8v*)(Ah + (wm * 64 + i * 16 + fr) * LDT + kk);
                b2[i] = *(const half8v*)(Bh + (wn * 64 + i * 16 + fr) * LDT + kk);
            }
#pragma unroll
            for (int i = 0; i < 4; ++i)
#pragma unroll
                for (int j = 0; j < 4; ++j)
                    acc[i][j] = __builtin_amdgcn_mfma_f32_16x16x32_f16(
                        a2[i], b2[j], acc[i][j], 0, 0, 0);
        }
        __syncthreads();
    }

#pragma unroll
    for (int i = 0; i < 4; ++i) {
        const long mrow = m0 + wm * 64 + i * 16 + (lane >> 4) * 4;
#pragma unroll
        for (int j = 0; j < 4; ++j) {
            const long col = n0 + wn * 64 + j * 16 + (lane & 15);
            const float b = bias[col];
#pragma unroll
            for (int r = 0; r < 4; ++r)
                Y[(mrow + r) * N_DIM + col] = acc[i][j][r] + b;
        }
    }
}

extern "C" void kernel_launch(void* const* d_in, const int* in_sizes, int n_in,
                              void* d_out, int out_size, void* d_ws, size_t ws_size,
                              hipStream_t stream)
{
    const float* X  = (const float*)d_in[0];
    const int*   qp = (const int*)d_in[1];
    const float* sc = (const float*)d_in[2];
    const float* zr = (const float*)d_in[3];
    const float* dwt = (const float*)d_in[4];
    const float* bs = (const float*)d_in[5];
    float* Y = (float*)d_out;

    const size_t needB = (size_t)N_DIM * K_DIM * 2;   // 33.5 MB
    const size_t needA = (size_t)M_DIM * K_DIM * 2;   // 67.1 MB

    if (ws_size >= needA + needB) {
        unsigned char* Bpk = (unsigned char*)d_ws;
        unsigned char* Apk = Bpk + needB;
        k_pack_w<<<dim3((unsigned)(needB >> 12)), dim3(256), 0, stream>>>(qp, sc, zr, dwt, Bpk);
        k_pack_x<<<dim3((unsigned)(needA >> 12)), dim3(256), 0, stream>>>(X, Apk);
        k_gemm_occ<<<dim3((M_DIM / 128) * (N_DIM / 256)), dim3(512), 0, stream>>>(Apk, Bpk, bs, Y);
    } else {
        k_gemm_fused<<<dim3((M_DIM / 128) * (N_DIM / 128)), dim3(256), 0, stream>>>(
            X, qp, sc, zr, dwt, bs, Y);
    }
}

// Round 10
// 267.891 us; speedup vs baseline: 1.1406x; 1.1406x over previous
//
#include <hip/hip_runtime.h>

// y[m,o] = sum_k x[m,k] * (W[o,k] + dW[o,k]) + bias[o],  W int4-dequant.
// M=8192, N=4096(OUT), K=4096(IN).
//
// Round 10: r7 structure (validated: 256x256, 8-phase, 4 barriers/iter,
// frag-packed tiles, gather packs, vmcnt(4) at p3/p7) with dtype f16 -> bf16:
//   - packs emit RNE bf16 (ushort bit pattern)
//   - GEMM frags are short8, mfma_f32_16x16x32_bf16 (C/D layout identical)
//   - plain Y stores (nt stores amplified WRITE_SIZE 131->178MB at 16x16)
// Ceiling: bf16 16x16 = 2075 TF ubench vs f16 1955 (+6%).

#define M_DIM 8192
#define N_DIM 4096
#define K_DIM 4096
#define NUMEL (N_DIM * K_DIM)

typedef _Float16 half_t;
typedef __attribute__((ext_vector_type(4))) _Float16 half4v;
typedef __attribute__((ext_vector_type(8))) _Float16 half8v;
typedef __attribute__((ext_vector_type(8))) short short8v;
typedef __attribute__((ext_vector_type(8))) unsigned short ushort8v;
typedef __attribute__((ext_vector_type(4))) float float4v;
typedef __attribute__((ext_vector_type(4))) int int4v;

#define KTILES 64                // K/64
#define LDT 72                   // fused-fallback padded row stride

static __device__ __forceinline__ void gload16(const void* g, void* l) {
    __builtin_amdgcn_global_load_lds(
        (const __attribute__((address_space(1))) void*)g,
        (__attribute__((address_space(3))) void*)l, 16, 0, 0);
}

// float -> bf16 bits, round-to-nearest-even (inputs are finite, well-scaled)
static __device__ __forceinline__ unsigned short f2bf(float f) {
    unsigned u = __builtin_bit_cast(unsigned, f);
    u += 0x7fffu + ((u >> 16) & 1u);
    return (unsigned short)(u >> 16);
}

// ---------- Phase 1a: dequant+delta -> bf16, fragment-packed (gather) ------
// 16KB tile = 128 rows x 64 k. frag(rt,ks) 1KB: lane = (row&15)+16*((k&31)>>3),
// bytes (k&7)*2. chunk index = rt*2 + ks.
__global__ __launch_bounds__(256) void k_pack_w(
    const int* __restrict__ qp, const float* __restrict__ sc,
    const float* __restrict__ zr, const float* __restrict__ dwt,
    unsigned char* __restrict__ Wp)
{
    const size_t o = ((size_t)blockIdx.x * 256 + threadIdx.x) << 4;
    const int chunk16 = (int)(o >> 14);          // panel*64 + kt
    const int c  = (int)(o >> 10) & 15;          // rt*2 + ks
    const int ln = (int)(o >> 4) & 63;
    const int n = (chunk16 >> 6) * 128 + (c >> 1) * 16 + (ln & 15);
    const int k = (chunk16 & 63) * 64 + (c & 1) * 32 + (ln >> 4) * 8;
    const long flat = (long)n * K_DIM + k;
    const int g = n * 32 + (k >> 7);
    const float s = sc[g];
    const float zs = zr[g] * s;
    int4v q4 = *(const int4v*)(qp + (flat >> 1));
    float4v d0 = *(const float4v*)(dwt + flat);
    float4v d1 = *(const float4v*)(dwt + flat + 4);
    float d[8] = {d0[0], d0[1], d0[2], d0[3], d1[0], d1[1], d1[2], d1[3]};
    ushort8v vh;
#pragma unroll
    for (int j = 0; j < 4; ++j) {
        vh[2*j]   = f2bf(fmaf((float)(q4[j] & 15),        s, d[2*j]   - zs));
        vh[2*j+1] = f2bf(fmaf((float)((q4[j] >> 4) & 15), s, d[2*j+1] - zs));
    }
    *(ushort8v*)(Wp + o) = vh;
}

// ---------- Phase 1b: x fp32 -> bf16, fragment-packed (gather) ----------
__global__ __launch_bounds__(256) void k_pack_x(
    const float* __restrict__ X, unsigned char* __restrict__ Xp)
{
    const size_t o = ((size_t)blockIdx.x * 256 + threadIdx.x) << 4;
    const int chunk16 = (int)(o >> 14);
    const int c  = (int)(o >> 10) & 15;
    const int ln = (int)(o >> 4) & 63;
    const int m = (chunk16 >> 6) * 128 + (c >> 1) * 16 + (ln & 15);
    const int k = (chunk16 & 63) * 64 + (c & 1) * 32 + (ln >> 4) * 8;
    const float* src = X + (size_t)m * K_DIM + k;
    float4v x0 = *(const float4v*)(src);
    float4v x1 = *(const float4v*)(src + 4);
    ushort8v vh;
    vh[0] = f2bf(x0[0]); vh[1] = f2bf(x0[1]);
    vh[2] = f2bf(x0[2]); vh[3] = f2bf(x0[3]);
    vh[4] = f2bf(x1[0]); vh[5] = f2bf(x1[1]);
    vh[6] = f2bf(x1[2]); vh[7] = f2bf(x1[3]);
    *(ushort8v*)(Xp + o) = vh;
}

// ---------- 8-phase 256x256 GEMM, bf16 16x16x32, frag-packed ----------
#define BARX() do { __builtin_amdgcn_sched_barrier(0); \
                    __builtin_amdgcn_s_barrier(); \
                    __builtin_amdgcn_sched_barrier(0); } while(0)
#define WAITV(N) do { asm volatile("s_waitcnt vmcnt(" #N ")" ::: "memory"); \
                      __builtin_amdgcn_sched_barrier(0); } while(0)

#define READ_A(BUF, F0) do { \
_Pragma("unroll") for (int i_ = 0; i_ < 4; ++i_) \
_Pragma("unroll") for (int ks_ = 0; ks_ < 2; ++ks_) \
        ah[i_][ks_] = *(const short8v*)(&lds[BUF][wm] \
            [((((F0) + i_) * 2 + ks_) << 10) + lane16]); \
    } while(0)

#define READ_B(BUF, DST, J0) do { \
_Pragma("unroll") for (int j_ = 0; j_ < 2; ++j_) \
_Pragma("unroll") for (int ks_ = 0; ks_ < 2; ++ks_) \
        DST[j_][ks_] = *(const short8v*)(&lds[BUF][bhalf] \
            [bq8192 + ((((J0) + j_) * 2 + ks_) << 10) + lane16]); \
    } while(0)

#define MFMA_Q(F0, N0, BREG) do { \
    __builtin_amdgcn_s_setprio(1); \
_Pragma("unroll") for (int i_ = 0; i_ < 4; ++i_) \
_Pragma("unroll") for (int j_ = 0; j_ < 2; ++j_) \
_Pragma("unroll") for (int ks_ = 0; ks_ < 2; ++ks_) \
        acc[(F0)+i_][(N0)+j_] = __builtin_amdgcn_mfma_f32_16x16x32_bf16( \
            ah[i_][ks_], BREG[j_][ks_], acc[(F0)+i_][(N0)+j_], 0, 0, 0); \
    __builtin_amdgcn_s_setprio(0); \
} while(0)

__global__ __launch_bounds__(512, 2) void k_gemm8ph(
    const unsigned char* __restrict__ Apk, const unsigned char* __restrict__ Bpk,
    const float* __restrict__ bias, float* __restrict__ Y)
{
    __shared__ __align__(16) unsigned char lds[2][4][16384];  // [buf][A0,A1,B0,B1]

    const int tid  = threadIdx.x;
    const int lane = tid & 63;
    const int wave = tid >> 6;
    const int wm = wave >> 2;
    const int wn = wave & 3;
    const int bhalf = 2 + (wn >> 1);
    const int bq8192 = (wn & 1) << 13;     // wave's 8KB quarter within B half
    const int lane16 = lane << 4;

    const int wg = blockIdx.x;
    const int swg = (wg & 7) * 64 + (wg >> 3);   // 512 blocks, 8 XCDs, bijective
    const int bn = swg & 15;
    const int bm = swg >> 4;

    auto asrc = [&](int h, int tk) {
        return Apk + ((((size_t)(2 * bm + h)) * KTILES + tk) << 14);
    };
    auto bsrc = [&](int h, int tk) {
        return Bpk + ((((size_t)(2 * bn + h)) * KTILES + tk) << 14);
    };
    auto stageh = [&](int b, int h, const unsigned char* s) {
        unsigned char* d = &lds[b][h][tid << 4];
        gload16(s + (tid << 4), d);
        gload16(s + 8192 + (tid << 4), d + 8192);
    };

    short8v ah[4][2], b01[2][2], b23[2][2];
    float4v acc[8][4];
    const float4v zero4 = {0.f, 0.f, 0.f, 0.f};
#pragma unroll
    for (int i = 0; i < 8; ++i)
#pragma unroll
        for (int j = 0; j < 4; ++j) acc[i][j] = zero4;

    // ---- prologue: tile0 -> buf0 (4 halves); B(tile1) -> buf1 ----
    stageh(0, 0, asrc(0, 0)); stageh(0, 1, asrc(1, 0));
    stageh(0, 2, bsrc(0, 0)); stageh(0, 3, bsrc(1, 0));
    stageh(1, 2, bsrc(0, 1)); stageh(1, 3, bsrc(1, 1));
    WAITV(4);
    BARX();

    for (int it = 0; it < 31; ++it) {
        const int t1 = 2 * it + 1, t2 = 2 * it + 2, t3 = 2 * it + 3;
        // p0: read buf0 A[0-3],B[0-1]; stage S0 = A(buf1,t1)   [no barrier]
        READ_A(0, 0); READ_B(0, b01, 0);
        stageh(1, 0, asrc(0, t1)); stageh(1, 1, asrc(1, t1));
        MFMA_Q(0, 0, b01);
        // p1: read B[2-3](buf0)                                 [no barrier]
        READ_B(0, b23, 2);
        MFMA_Q(0, 2, b23);
        // p2: read A[4-7](buf0)
        READ_A(0, 4);
        BARX();
        MFMA_Q(4, 2, b23);
        // p3: stage S3 = B(buf0,t2); drain for buf1 t1
        stageh(0, 2, bsrc(0, t2)); stageh(0, 3, bsrc(1, t2));
        WAITV(4);
        BARX();
        MFMA_Q(4, 0, b01);
        // p4: read buf1 A[0-3],B[0-1]; stage S4 = A(buf0,t2)    [no barrier]
        READ_A(1, 0); READ_B(1, b01, 0);
        stageh(0, 0, asrc(0, t2)); stageh(0, 1, asrc(1, t2));
        MFMA_Q(0, 0, b01);
        // p5                                                    [no barrier]
        READ_B(1, b23, 2);
        MFMA_Q(0, 2, b23);
        // p6
        READ_A(1, 4);
        BARX();
        MFMA_Q(4, 2, b23);
        // p7: stage S7 = B(buf1,t3); drain for buf0 t2
        stageh(1, 2, bsrc(0, t3)); stageh(1, 3, bsrc(1, t3));
        WAITV(4);
        BARX();
        MFMA_Q(4, 0, b01);
    }

    // ---- tail: K-tiles 62 (buf0), 63 (buf1); conservative barriers ----
    READ_A(0, 0); READ_B(0, b01, 0);
    stageh(1, 0, asrc(0, 63)); stageh(1, 1, asrc(1, 63));
    BARX(); MFMA_Q(0, 0, b01);
    READ_B(0, b23, 2);
    BARX(); MFMA_Q(0, 2, b23);
    READ_A(0, 4);
    BARX(); MFMA_Q(4, 2, b23);
    WAITV(0);                      // drain: buf1 tile63 fully staged
    BARX(); MFMA_Q(4, 0, b01);
    READ_A(1, 0); READ_B(1, b01, 0);
    BARX(); MFMA_Q(0, 0, b01);
    READ_B(1, b23, 2);
    BARX(); MFMA_Q(0, 2, b23);
    READ_A(1, 4);
    BARX(); MFMA_Q(4, 2, b23);
    MFMA_Q(4, 0, b01);

    // ---- epilogue: 16x16 C/D map col=lane&15, row=(lane>>4)*4+reg ----
    const long m0 = (long)bm * 256 + wm * 128;
    const long n0 = (long)bn * 256 + wn * 64;
#pragma unroll
    for (int mf = 0; mf < 8; ++mf) {
        const long row = m0 + mf * 16 + (lane >> 4) * 4;
#pragma unroll
        for (int nf = 0; nf < 4; ++nf) {
            const long col = n0 + nf * 16 + (lane & 15);
            const float b = bias[col];
#pragma unroll
            for (int r = 0; r < 4; ++r)
                Y[(row + r) * N_DIM + col] = acc[mf][nf][r] + b;
        }
    }
}

// ---------- fallback (no workspace): fused dequant 128x128 GEMM ----------
__global__ __launch_bounds__(256, 2) void k_gemm_fused(
    const float* __restrict__ X, const int* __restrict__ qp,
    const float* __restrict__ sc, const float* __restrict__ zr,
    const float* __restrict__ dwt,
    const float* __restrict__ bias, float* __restrict__ Y)
{
    __shared__ __align__(16) half_t Ah[128 * LDT];
    __shared__ __align__(16) half_t Bh[128 * LDT];

    const int tid  = threadIdx.x;
    const int lane = tid & 63;
    const int wave = tid >> 6;
    const int wm = wave >> 1, wn = wave & 1;
    const int bn = blockIdx.x & 31;
    const int bm = blockIdx.x >> 5;
    const long m0 = (long)bm * 128;
    const long n0 = (long)bn * 128;
    const int fr = lane & 15;
    const int ko = (lane >> 4) * 8;

    const float4v zero4 = {0.f, 0.f, 0.f, 0.f};
    float4v acc[4][4];
#pragma unroll
    for (int i = 0; i < 4; ++i)
#pragma unroll
        for (int j = 0; j < 4; ++j) acc[i][j] = zero4;

    for (int k0 = 0; k0 < K_DIM; k0 += 64) {
        {
            const int ar = tid >> 4;
            const int ac = (tid & 15) * 4;
#pragma unroll
            for (int rr = 0; rr < 8; ++rr) {
                const int row = ar + rr * 16;
                float4v xv = *(const float4v*)(X + (m0 + row) * K_DIM + k0 + ac);
                half4v h;
#pragma unroll
                for (int j = 0; j < 4; ++j) h[j] = (half_t)xv[j];
                *(half4v*)(Ah + row * LDT + ac) = h;
            }
        }
        {
            const int cr = tid >> 3;
            const int cc = (tid & 7) * 8;
#pragma unroll
            for (int rr = 0; rr < 4; ++rr) {
                const int row = cr + rr * 32;
                const long n = n0 + row;
                const int g = (int)(n * 32 + (k0 >> 7));
                const float s = sc[g];
                const float zs = zr[g] * s;
                const long flat = n * K_DIM + k0 + cc;
                int4v q4 = *(const int4v*)(qp + (flat >> 1));
                float4v d0 = *(const float4v*)(dwt + flat);
                float4v d1 = *(const float4v*)(dwt + flat + 4);
                float d[8] = {d0[0], d0[1], d0[2], d0[3], d1[0], d1[1], d1[2], d1[3]};
                half8v vh;
#pragma unroll
                for (int j = 0; j < 4; ++j) {
                    vh[2*j]   = (half_t)fmaf((float)(q4[j] & 15),        s, d[2*j]   - zs);
                    vh[2*j+1] = (half_t)fmaf((float)((q4[j] >> 4) & 15), s, d[2*j+1] - zs);
                }
                *(half8v*)(Bh + row * LDT + cc) = vh;
            }
        }
        __syncthreads();
#pragma unroll
        for (int ks = 0; ks < 2; ++ks) {
            const int kk = ks * 32 + ko;
            half8v a2[4], b2[4];
#pragma unroll
            for (int i = 0; i < 4; ++i) {
                a2[i] = *(const half8v*)(Ah + (wm * 64 + i * 16 + fr) * LDT + kk);
                b2[i] = *(const half8v*)(Bh + (wn * 64 + i * 16 + fr) * LDT + kk);
            }
#pragma unroll
            for (int i = 0; i < 4; ++i)
#pragma unroll
                for (int j = 0; j < 4; ++j)
                    acc[i][j] = __builtin_amdgcn_mfma_f32_16x16x32_f16(
                        a2[i], b2[j], acc[i][j], 0, 0, 0);
        }
        __syncthreads();
    }

#pragma unroll
    for (int i = 0; i < 4; ++i) {
        const long mrow = m0 + wm * 64 + i * 16 + (lane >> 4) * 4;
#pragma unroll
        for (int j = 0; j < 4; ++j) {
            const long col = n0 + wn * 64 + j * 16 + (lane & 15);
            const float b = bias[col];
#pragma unroll
            for (int r = 0; r < 4; ++r)
                Y[(mrow + r) * N_DIM + col] = acc[i][j][r] + b;
        }
    }
}

extern "C" void kernel_launch(void* const* d_in, const int* in_sizes, int n_in,
                              void* d_out, int out_size, void* d_ws, size_t ws_size,
                              hipStream_t stream)
{
    const float* X  = (const float*)d_in[0];
    const int*   qp = (const int*)d_in[1];
    const float* sc = (const float*)d_in[2];
    const float* zr = (const float*)d_in[3];
    const float* dwt = (const float*)d_in[4];
    const float* bs = (const float*)d_in[5];
    float* Y = (float*)d_out;

    const size_t needB = (size_t)N_DIM * K_DIM * 2;   // 33.5 MB
    const size_t needA = (size_t)M_DIM * K_DIM * 2;   // 67.1 MB

    if (ws_size >= needA + needB) {
        unsigned char* Bpk = (unsigned char*)d_ws;
        unsigned char* Apk = Bpk + needB;
        k_pack_w<<<dim3((unsigned)(needB >> 12)), dim3(256), 0, stream>>>(qp, sc, zr, dwt, Bpk);
        k_pack_x<<<dim3((unsigned)(needA >> 12)), dim3(256), 0, stream>>>(X, Apk);
        k_gemm8ph<<<dim3((M_DIM / 256) * (N_DIM / 256)), dim3(512), 0, stream>>>(Apk, Bpk, bs, Y);
    } else {
        k_gemm_fused<<<dim3((M_DIM / 128) * (N_DIM / 128)), dim3(256), 0, stream>>>(
            X, qp, sc, zr, dwt, bs, Y);
    }
}